// Round 2
// baseline (239.333 us; speedup 1.0000x reference)
//
#include <hip/hip_runtime.h>
#include <stdint.h>

typedef __attribute__((ext_vector_type(4))) float f32x4;
typedef __attribute__((ext_vector_type(8))) __bf16 bf16x8;
typedef __attribute__((ext_vector_type(4))) unsigned int u32x4;
typedef unsigned short u16;

#define B_DIM 2
#define T_DIM 2048
#define C_DIM 2048
#define H_Q   16
#define H_KV  4
#define HD    128
#define NQKV  3072            // 2048 q | 512 k | 512 v
#define MTOK  4096            // B*T
#define RMS_EPS 1.1920928955078125e-07f

__device__ __forceinline__ u16 f2bf(float f) {
  union { float f; unsigned int u; } v; v.f = f;
  unsigned int r = v.u + 0x7FFFu + ((v.u >> 16) & 1u);   // RNE
  return (u16)(r >> 16);
}
__device__ __forceinline__ float bf2f(u16 h) {
  union { unsigned int u; float f; } v; v.u = ((unsigned int)h) << 16;
  return v.f;
}
__device__ __forceinline__ f32x4 mfma16(bf16x8 a, bf16x8 b, f32x4 c) {
  return __builtin_amdgcn_mfma_f32_16x16x32_bf16(a, b, c, 0, 0, 0);
}
// async global->LDS, 16B per lane; lds base must be wave-uniform (HW: base + lane*16)
__device__ __forceinline__ void gl_lds16(const void* g, void* l) {
  __builtin_amdgcn_global_load_lds(
      (const __attribute__((address_space(1))) unsigned int*)g,
      (__attribute__((address_space(3))) unsigned int*)l, 16, 0, 0);
}

// ---------------- cast x fp32 -> bf16 ----------------
__global__ __launch_bounds__(256) void cast_x_kernel(const float* __restrict__ x,
                                                     u16* __restrict__ xb, int n) {
  int i = (blockIdx.x * 256 + threadIdx.x) * 4;
  if (i >= n) return;
  float4 v = *(const float4*)(x + i);
  u16 o0 = f2bf(v.x), o1 = f2bf(v.y), o2 = f2bf(v.z), o3 = f2bf(v.w);
  unsigned int lo = (unsigned int)o0 | ((unsigned int)o1 << 16);
  unsigned int hi = (unsigned int)o2 | ((unsigned int)o3 << 16);
  *(uint2*)(xb + i) = make_uint2(lo, hi);
}

// ---------------- transpose + cast: in fp32 [K][N] -> out bf16 [N][K] ----------------
__global__ __launch_bounds__(256) void transpose_cast_kernel(const float* __restrict__ in,
                                                             u16* __restrict__ out,
                                                             int K, int N) {
  __shared__ float tile[64][65];
  int n0 = blockIdx.x * 64, k0 = blockIdx.y * 64;
  int t = threadIdx.x;
  #pragma unroll
  for (int idx = t; idx < 4096; idx += 256) {
    int r = idx >> 6, c = idx & 63;
    tile[r][c] = in[(size_t)(k0 + r) * N + n0 + c];
  }
  __syncthreads();
  #pragma unroll
  for (int idx = t; idx < 4096; idx += 256) {
    int r = idx >> 6, c = idx & 63;
    out[(size_t)(n0 + r) * K + k0 + c] = f2bf(tile[c][r]);
  }
}

// ---------------- RoPE + RMS-norm in place on q,k columns of qkv (bf16) ----------------
__global__ __launch_bounds__(256) void rope_rms_kernel(u16* __restrict__ qkv,
                                                       const float* __restrict__ cosb,
                                                       const float* __restrict__ sinb) {
  int gw = (blockIdx.x * 256 + threadIdx.x) >> 6;   // one wave per (token, head)
  int lane = threadIdx.x & 63;
  int hh = gw % (H_Q + H_KV);
  int tok = gw / (H_Q + H_KV);
  int t = tok & (T_DIM - 1);
  int base = (hh < H_Q) ? hh * HD : (C_DIM + (hh - H_Q) * HD);
  u16* p = qkv + (size_t)tok * NQKV + base;
  float x1 = bf2f(p[lane]);
  float x2 = bf2f(p[lane + 64]);
  float c = cosb[t * 64 + lane];
  float s = sinb[t * 64 + lane];
  float o1 =  x1 * c + x2 * s;
  float o2 = -x1 * s + x2 * c;
  float ss = o1 * o1 + o2 * o2;
  #pragma unroll
  for (int off = 1; off < 64; off <<= 1) ss += __shfl_xor(ss, off);
  float r = rsqrtf(ss * (1.0f / 128.0f) + RMS_EPS);
  p[lane]      = f2bf(o1 * r);
  p[lane + 64] = f2bf(o2 * r);
}

// ---------------- V^T precompute: qkv v-section -> vt[b][kvh][d][T] ----------------
__global__ __launch_bounds__(256) void vtrans_kernel(const u16* __restrict__ qkv,
                                                     u16* __restrict__ vt) {
  __shared__ __align__(16) u16 tile[64][136];       // 64 t x 128 d, padded
  int bid = blockIdx.x;
  int tt0 = (bid & 31) * 64;
  int kvh = (bid >> 5) & 3;
  int b   = bid >> 7;
  const u16* vp = qkv + ((size_t)b * T_DIM + tt0) * NQKV + C_DIM + H_KV * HD + kvh * HD;
  int tid = threadIdx.x;
  #pragma unroll
  for (int i = 0; i < 4; ++i) {
    int cid = tid + i * 256;            // 1024 = 64 rows x 16 chunks
    int r = cid >> 4, c = cid & 15;
    u32x4 v = *(const u32x4*)(vp + (size_t)r * NQKV + c * 8);
    *(u32x4*)&tile[r][c * 8] = v;
  }
  __syncthreads();
  u16* op = vt + ((size_t)(b * H_KV + kvh) * HD) * T_DIM + tt0;
  #pragma unroll
  for (int i = 0; i < 4; ++i) {
    int cid = tid + i * 256;            // 1024 = 128 d x 8 t-chunks
    int d = cid >> 3, tc = cid & 7;
    u16 vals[8];
    #pragma unroll
    for (int j = 0; j < 8; ++j) vals[j] = tile[tc * 8 + j][d];
    u32x4 w;
    w.x = (unsigned int)vals[0] | ((unsigned int)vals[1] << 16);
    w.y = (unsigned int)vals[2] | ((unsigned int)vals[3] << 16);
    w.z = (unsigned int)vals[4] | ((unsigned int)vals[5] << 16);
    w.w = (unsigned int)vals[6] | ((unsigned int)vals[7] << 16);
    *(u32x4*)(op + (size_t)d * T_DIM + tc * 8) = w;
  }
}

// ---------------- bf16 GEMM: C[M][N] = A[M][K] * Bt[N][K]^T ----------------
// 128x128 tile, BK=64, 4 waves. global_load_lds staging, source pre-swizzled so
// linear LDS writes yield XOR-swizzled content (conflict-free ds_read_b128).
template<int BF16OUT>
__global__ __launch_bounds__(256) void gemm_bt_kernel(const u16* __restrict__ A,
                                                      const u16* __restrict__ Bt,
                                                      void* __restrict__ Cv,
                                                      int M, int N, int K) {
  __shared__ __align__(16) u16 Asm[128 * 64];
  __shared__ __align__(16) u16 Bsm[128 * 64];
  const int tid = threadIdx.x;
  const int lane = tid & 63;
  const int wid = tid >> 6;
  const int m0 = blockIdx.y * 128, n0 = blockIdx.x * 128;
  const int wm = (wid >> 1) * 64, wn = (wid & 1) * 64;
  const int l15 = lane & 15, l4 = lane >> 4;
  const int csrc = (lane & 7) ^ (lane >> 3);      // pre-swizzled source chunk
  f32x4 acc[4][4] = {};

  for (int k0 = 0; k0 < K; k0 += 64) {
    __syncthreads();
    #pragma unroll
    for (int i = 0; i < 4; ++i) {                 // 4 issues/wave/operand, 1KB each
      int g = wid * 4 + i;
      int row = g * 8 + (lane >> 3);
      gl_lds16(A  + (size_t)(m0 + row) * K + k0 + csrc * 8, (char*)Asm + g * 1024);
      gl_lds16(Bt + (size_t)(n0 + row) * K + k0 + csrc * 8, (char*)Bsm + g * 1024);
    }
    __syncthreads();                              // drains vmcnt (compiler-inserted)
    #pragma unroll
    for (int ks = 0; ks < 2; ++ks) {
      bf16x8 af[4], bfr[4];
      #pragma unroll
      for (int mf = 0; mf < 4; ++mf) {
        int r = wm + mf * 16 + l15;
        int bo = r * 128 + (((ks * 4 + l4) ^ (r & 7)) * 16);
        af[mf] = __builtin_bit_cast(bf16x8, *(const u32x4*)((const char*)Asm + bo));
      }
      #pragma unroll
      for (int nf = 0; nf < 4; ++nf) {
        int r = wn + nf * 16 + l15;
        int bo = r * 128 + (((ks * 4 + l4) ^ (r & 7)) * 16);
        bfr[nf] = __builtin_bit_cast(bf16x8, *(const u32x4*)((const char*)Bsm + bo));
      }
      #pragma unroll
      for (int mf = 0; mf < 4; ++mf)
        #pragma unroll
        for (int nf = 0; nf < 4; ++nf)
          acc[mf][nf] = mfma16(af[mf], bfr[nf], acc[mf][nf]);
    }
  }
  #pragma unroll
  for (int mf = 0; mf < 4; ++mf)
    #pragma unroll
    for (int nf = 0; nf < 4; ++nf)
      #pragma unroll
      for (int reg = 0; reg < 4; ++reg) {
        int row = m0 + wm + mf * 16 + l4 * 4 + reg;
        int col = n0 + wn + nf * 16 + l15;
        float v = acc[mf][nf][reg];
        if (BF16OUT) ((u16*)Cv)[(size_t)row * N + col] = f2bf(v);
        else         ((float*)Cv)[(size_t)row * N + col] = v;
      }
}

// ---------------- sliding-window GQA flash attention ----------------
// Block = 128 q-rows of one (b,h); 4 waves x 32 rows (2 frags). K-tiles of 64.
// K and V^T staged via global_load_lds with pre-swizzled source.
__global__ __launch_bounds__(256) void attn_kernel(const u16* __restrict__ qkv,
                                                   const u16* __restrict__ vt,
                                                   u16* __restrict__ yb,
                                                   const int* __restrict__ wsz_p) {
  __shared__ __align__(16) u16 Ksm[64 * 128];     // [key][d], 16-chunk swizzle ^(key&15)
  __shared__ __align__(16) u16 Vsm[128 * 64];     // [d][key], 8-chunk swizzle ^(d&7)
  __shared__ __align__(16) u16 Psm[4 * 32 * 64];  // per-wave P 32x64, swizzle ^(q&7)

  const int W = wsz_p[0];
  const int tid = threadIdx.x, lane = tid & 63, wid = tid >> 6;
  const int l15 = lane & 15, l4 = lane >> 4;
  const int bid = blockIdx.x;
  const int qt  = bid & 15;              // T/128
  const int h   = (bid >> 4) & 15;
  const int b   = bid >> 8;
  const int kvh = h >> 2;                // rep = 4
  const size_t tokb = (size_t)b * T_DIM;
  const u16* vtb = vt + ((size_t)(b * H_KV + kvh) * HD) * T_DIM;
  const int rbase = qt * 128 + wid * 32;

  // Q fragments (A-layout: row = lane&15, k = (lane>>4)*8 + j)
  bf16x8 qf[2][4];
  #pragma unroll
  for (int mf = 0; mf < 2; ++mf) {
    int r = rbase + mf * 16 + l15;
    const u16* qp = qkv + (tokb + r) * NQKV + h * HD;
    #pragma unroll
    for (int ks = 0; ks < 4; ++ks)
      qf[mf][ks] = __builtin_bit_cast(bf16x8, *(const u32x4*)(qp + ks * 32 + l4 * 8));
  }

  f32x4 yacc[2][8] = {};
  float mrow[2][4], lrow[2][4];
  #pragma unroll
  for (int mf = 0; mf < 2; ++mf)
    #pragma unroll
    for (int rg = 0; rg < 4; ++rg) { mrow[mf][rg] = -3.0e38f; lrow[mf][rg] = 0.0f; }

  const float sc = 0.08838834764831845f * 1.4426950408889634f; // 1/sqrt(128)*log2(e)
  int smin = qt * 128 - W; if (smin < 0) smin = 0;
  const int t0 = smin >> 6;
  const int t1 = qt * 2 + 1;

  for (int kt = t0; kt <= t1; ++kt) {
    __syncthreads();
    { // stage K: 16 issues (4/wave), 1KB = 4 key-rows each
      const u16* kp = qkv + (tokb + kt * 64) * NQKV + C_DIM + kvh * HD;
      #pragma unroll
      for (int i = 0; i < 4; ++i) {
        int g = wid * 4 + i;
        int row = g * 4 + (lane >> 4);
        int cs = (lane & 15) ^ (row & 15);
        gl_lds16(kp + (size_t)row * NQKV + cs * 8, (char*)Ksm + g * 1024);
      }
    }
    { // stage V^T: 16 issues (4/wave), 1KB = 8 d-rows each
      const u16* vp = vtb + kt * 64;
      #pragma unroll
      for (int i = 0; i < 4; ++i) {
        int g = wid * 4 + i;
        int d = g * 8 + (lane >> 3);
        int cs = (lane & 7) ^ (d & 7);
        gl_lds16(vp + (size_t)d * T_DIM + cs * 8, (char*)Vsm + g * 1024);
      }
    }
    __syncthreads();

    const int slo = kt * 64;
    // per-wave skip of fully-masked tiles (no barriers inside)
    bool active = (slo <= rbase + 31) && ((rbase - (slo + 63)) <= W);
    if (active) {
      float fmul[2][4];
      char* pbase = (char*)Psm + wid * 4096;
      #pragma unroll
      for (int mf = 0; mf < 2; ++mf) {
        const int rb = rbase + mf * 16;
        // S = Q K^T
        float Sc[4][4];
        #pragma unroll
        for (int nf = 0; nf < 4; ++nf) {
          f32x4 sa = {0.f, 0.f, 0.f, 0.f};
          int key = nf * 16 + l15;
          #pragma unroll
          for (int ks = 0; ks < 4; ++ks) {
            int bo = key * 256 + (((ks * 4 + l4) ^ (key & 15)) * 16);
            bf16x8 kf = __builtin_bit_cast(bf16x8, *(const u32x4*)((const char*)Ksm + bo));
            sa = mfma16(qf[mf][ks], kf, sa);
          }
          #pragma unroll
          for (int rg = 0; rg < 4; ++rg) Sc[nf][rg] = sa[rg] * sc;
        }
        // mask
        bool fullvalid = ((slo + 63) <= rb) && ((rb + 15 - slo) <= W);
        if (!fullvalid) {
          #pragma unroll
          for (int nf = 0; nf < 4; ++nf) {
            int s = slo + nf * 16 + l15;
            #pragma unroll
            for (int rg = 0; rg < 4; ++rg) {
              int r = rb + l4 * 4 + rg;
              if (s > r || (r - s) > W) Sc[nf][rg] = -3.0e38f;
            }
          }
        }
        // online softmax (exp2 domain)
        #pragma unroll
        for (int rg = 0; rg < 4; ++rg) {
          float tm = fmaxf(fmaxf(Sc[0][rg], Sc[1][rg]), fmaxf(Sc[2][rg], Sc[3][rg]));
          #pragma unroll
          for (int off = 1; off < 16; off <<= 1) tm = fmaxf(tm, __shfl_xor(tm, off));
          float mnew = fmaxf(mrow[mf][rg], tm);
          float mo = fmaxf(mrow[mf][rg], -1.0e30f);
          float mc = fmaxf(mnew,         -1.0e30f);
          fmul[mf][rg] = exp2f(mo - mc);
          mrow[mf][rg] = mnew;
        }
        float rs[4] = {0.f, 0.f, 0.f, 0.f};
        #pragma unroll
        for (int nf = 0; nf < 4; ++nf)
          #pragma unroll
          for (int rg = 0; rg < 4; ++rg) {
            float mc = fmaxf(mrow[mf][rg], -1.0e30f);
            float pv = exp2f(Sc[nf][rg] - mc);
            rs[rg] += pv;
            // P -> wave-private LDS (bf16, swizzled for A-frag reads)
            int q   = mf * 16 + l4 * 4 + rg;
            int key = nf * 16 + l15;
            int bo = q * 128 + (((key >> 3) ^ (q & 7)) * 16) + (key & 7) * 2;
            *(u16*)(pbase + bo) = f2bf(pv);
          }
        #pragma unroll
        for (int rg = 0; rg < 4; ++rg) {
          #pragma unroll
          for (int off = 1; off < 16; off <<= 1) rs[rg] += __shfl_xor(rs[rg], off);
          lrow[mf][rg] = lrow[mf][rg] * fmul[mf][rg] + rs[rg];
        }
        f32x4 fv = {fmul[mf][0], fmul[mf][1], fmul[mf][2], fmul[mf][3]};
        #pragma unroll
        for (int nf2 = 0; nf2 < 8; ++nf2) yacc[mf][nf2] *= fv;
      }
      // PV: y(32 x 128) += P(32 x 64) @ V(64 x 128)
      #pragma unroll
      for (int ks2 = 0; ks2 < 2; ++ks2) {
        bf16x8 pa[2];
        #pragma unroll
        for (int mf = 0; mf < 2; ++mf) {
          int qr = mf * 16 + l15;
          int boA = qr * 128 + (((ks2 * 4 + l4) ^ (qr & 7)) * 16);
          pa[mf] = __builtin_bit_cast(bf16x8, *(const u32x4*)(pbase + boA));
        }
        #pragma unroll
        for (int nf2 = 0; nf2 < 8; ++nf2) {
          int d = nf2 * 16 + l15;
          int boB = d * 128 + (((ks2 * 4 + l4) ^ (d & 7)) * 16);
          bf16x8 vf = __builtin_bit_cast(bf16x8, *(const u32x4*)((const char*)Vsm + boB));
          yacc[0][nf2] = mfma16(pa[0], vf, yacc[0][nf2]);
          yacc[1][nf2] = mfma16(pa[1], vf, yacc[1][nf2]);
        }
      }
    }
  }

  // normalize + write y (bf16)
  #pragma unroll
  for (int mf = 0; mf < 2; ++mf)
    #pragma unroll
    for (int nf2 = 0; nf2 < 8; ++nf2)
      #pragma unroll
      for (int rg = 0; rg < 4; ++rg) {
        int r = rbase + mf * 16 + l4 * 4 + rg;
        float v = yacc[mf][nf2][rg] / lrow[mf][rg];
        yb[(tokb + r) * (size_t)C_DIM + h * HD + nf2 * 16 + l15] = f2bf(v);
      }
}

// ---------------- launch ----------------
extern "C" void kernel_launch(void* const* d_in, const int* in_sizes, int n_in,
                              void* d_out, int out_size, void* d_ws, size_t ws_size,
                              hipStream_t stream) {
  const float* x    = (const float*)d_in[0];
  const float* cosb = (const float*)d_in[1];
  const float* sinb = (const float*)d_in[2];
  const float* wq   = (const float*)d_in[3];
  const float* wk   = (const float*)d_in[4];
  const float* wv   = (const float*)d_in[5];
  const float* wo   = (const float*)d_in[6];
  const int*   wsz  = (const int*)d_in[7];

  char* ws = (char*)d_ws;
  u16* xb    = (u16*)(ws);                       // 16 MB (dead after QKV GEMM)
  u16* qkvb  = (u16*)(ws + (size_t)16777216);    // 24 MB
  u16* wqkvb = (u16*)(ws + (size_t)41943040);    // 12 MB, [3072][2048]
  u16* wob   = (u16*)(ws + (size_t)54525952);    // 8 MB,  [2048][2048]
  u16* ybuf  = (u16*)(ws + (size_t)62914560);    // 16 MB
  u16* vtb   = (u16*)(ws);                       // 4 MB, reuses xb region

  cast_x_kernel<<<8192, 256, 0, stream>>>(x, xb, MTOK * C_DIM);
  transpose_cast_kernel<<<dim3(32, 32), 256, 0, stream>>>(wq, wqkvb, 2048, 2048);
  transpose_cast_kernel<<<dim3(8, 32), 256, 0, stream>>>(wk, wqkvb + (size_t)2048 * 2048, 2048, 512);
  transpose_cast_kernel<<<dim3(8, 32), 256, 0, stream>>>(wv, wqkvb + (size_t)2560 * 2048, 2048, 512);
  transpose_cast_kernel<<<dim3(32, 32), 256, 0, stream>>>(wo, wob, 2048, 2048);

  gemm_bt_kernel<1><<<dim3(NQKV / 128, MTOK / 128), 256, 0, stream>>>(xb, wqkvb, qkvb, MTOK, NQKV, C_DIM);
  rope_rms_kernel<<<(MTOK * (H_Q + H_KV)) / 4, 256, 0, stream>>>(qkvb, cosb, sinb);
  vtrans_kernel<<<B_DIM * H_KV * (T_DIM / 64), 256, 0, stream>>>(qkvb, vtb);
  attn_kernel<<<B_DIM * H_Q * (T_DIM / 128), 256, 0, stream>>>(qkvb, vtb, ybuf, wsz);
  gemm_bt_kernel<0><<<dim3(C_DIM / 128, MTOK / 128), 256, 0, stream>>>(ybuf, wob, d_out, MTOK, C_DIM, C_DIM);
}

// Round 3
// 198.614 us; speedup vs baseline: 1.2050x; 1.2050x over previous
//
#include <hip/hip_runtime.h>
#include <stdint.h>

typedef __attribute__((ext_vector_type(4))) float f32x4;
typedef __attribute__((ext_vector_type(8))) __bf16 bf16x8;
typedef __attribute__((ext_vector_type(4))) unsigned int u32x4;
typedef unsigned short u16;

#define B_DIM 2
#define T_DIM 2048
#define C_DIM 2048
#define H_Q   16
#define H_KV  4
#define HD    128
#define NQKV  3072            // 2048 q | 512 k | 512 v
#define MTOK  4096            // B*T
#define RMS_EPS 1.1920928955078125e-07f

__device__ __forceinline__ u16 f2bf(float f) {
  union { float f; unsigned int u; } v; v.f = f;
  unsigned int r = v.u + 0x7FFFu + ((v.u >> 16) & 1u);   // RNE
  return (u16)(r >> 16);
}
__device__ __forceinline__ float bf2f(u16 h) {
  union { unsigned int u; float f; } v; v.u = ((unsigned int)h) << 16;
  return v.f;
}
__device__ __forceinline__ f32x4 mfma16(bf16x8 a, bf16x8 b, f32x4 c) {
  return __builtin_amdgcn_mfma_f32_16x16x32_bf16(a, b, c, 0, 0, 0);
}
// async global->LDS, 16B per lane; lds base must be wave-uniform (HW: base + lane*16)
__device__ __forceinline__ void gl_lds16(const void* g, void* l) {
  __builtin_amdgcn_global_load_lds(
      (const __attribute__((address_space(1))) unsigned int*)g,
      (__attribute__((address_space(3))) unsigned int*)l, 16, 0, 0);
}

// ---------------- cast x fp32 -> bf16 ----------------
__global__ __launch_bounds__(256) void cast_x_kernel(const float* __restrict__ x,
                                                     u16* __restrict__ xb, int n) {
  int i = (blockIdx.x * 256 + threadIdx.x) * 4;
  if (i >= n) return;
  float4 v = *(const float4*)(x + i);
  u16 o0 = f2bf(v.x), o1 = f2bf(v.y), o2 = f2bf(v.z), o3 = f2bf(v.w);
  unsigned int lo = (unsigned int)o0 | ((unsigned int)o1 << 16);
  unsigned int hi = (unsigned int)o2 | ((unsigned int)o3 << 16);
  *(uint2*)(xb + i) = make_uint2(lo, hi);
}

// ---------------- all 4 weight transposes in one kernel ----------------
// fp32 [K=2048][N] -> bf16 [N][2048];  nb<32: wq, <40: wk, <48: wv, else wo.
__global__ __launch_bounds__(256) void transpose_all_kernel(const float* __restrict__ wq,
                                                            const float* __restrict__ wk,
                                                            const float* __restrict__ wv,
                                                            const float* __restrict__ wo,
                                                            u16* __restrict__ wqkvb,
                                                            u16* __restrict__ wob) {
  __shared__ float tile[64][65];
  int nb = blockIdx.x, kb = blockIdx.y;
  const float* src; u16* dst; int srcN, nloc;
  if (nb < 32)      { src = wq; srcN = 2048; nloc = nb;      dst = wqkvb; }
  else if (nb < 40) { src = wk; srcN = 512;  nloc = nb - 32; dst = wqkvb + (size_t)2048 * 2048; }
  else if (nb < 48) { src = wv; srcN = 512;  nloc = nb - 40; dst = wqkvb + (size_t)2560 * 2048; }
  else              { src = wo; srcN = 2048; nloc = nb - 48; dst = wob; }
  int n0 = nloc * 64, k0 = kb * 64;
  int t = threadIdx.x;
  #pragma unroll
  for (int idx = t; idx < 4096; idx += 256) {
    int r = idx >> 6, c = idx & 63;
    tile[r][c] = src[(size_t)(k0 + r) * srcN + n0 + c];
  }
  __syncthreads();
  #pragma unroll
  for (int idx = t; idx < 4096; idx += 256) {
    int r = idx >> 6, c = idx & 63;
    dst[(size_t)(n0 + r) * 2048 + k0 + c] = f2bf(tile[c][r]);
  }
}

// ---------------- RoPE + RMS-norm in place on q,k columns of qkv (bf16) ----------------
__global__ __launch_bounds__(256) void rope_rms_kernel(u16* __restrict__ qkv,
                                                       const float* __restrict__ cosb,
                                                       const float* __restrict__ sinb) {
  int gw = (blockIdx.x * 256 + threadIdx.x) >> 6;   // one wave per (token, head)
  int lane = threadIdx.x & 63;
  int hh = gw % (H_Q + H_KV);
  int tok = gw / (H_Q + H_KV);
  int t = tok & (T_DIM - 1);
  int base = (hh < H_Q) ? hh * HD : (C_DIM + (hh - H_Q) * HD);
  u16* p = qkv + (size_t)tok * NQKV + base;
  float x1 = bf2f(p[lane]);
  float x2 = bf2f(p[lane + 64]);
  float c = cosb[t * 64 + lane];
  float s = sinb[t * 64 + lane];
  float o1 =  x1 * c + x2 * s;
  float o2 = -x1 * s + x2 * c;
  float ss = o1 * o1 + o2 * o2;
  #pragma unroll
  for (int off = 1; off < 64; off <<= 1) ss += __shfl_xor(ss, off);
  float r = rsqrtf(ss * (1.0f / 128.0f) + RMS_EPS);
  p[lane]      = f2bf(o1 * r);
  p[lane + 64] = f2bf(o2 * r);
}

// ---------------- V^T precompute: qkv v-section -> vt[b][kvh][d][T] ----------------
__global__ __launch_bounds__(256) void vtrans_kernel(const u16* __restrict__ qkv,
                                                     u16* __restrict__ vt) {
  __shared__ __align__(16) u16 tile[64][136];       // 64 t x 128 d, padded
  int bid = blockIdx.x;
  int tt0 = (bid & 31) * 64;
  int kvh = (bid >> 5) & 3;
  int b   = bid >> 7;
  const u16* vp = qkv + ((size_t)b * T_DIM + tt0) * NQKV + C_DIM + H_KV * HD + kvh * HD;
  int tid = threadIdx.x;
  #pragma unroll
  for (int i = 0; i < 4; ++i) {
    int cid = tid + i * 256;            // 1024 = 64 rows x 16 chunks
    int r = cid >> 4, c = cid & 15;
    u32x4 v = *(const u32x4*)(vp + (size_t)r * NQKV + c * 8);
    *(u32x4*)&tile[r][c * 8] = v;
  }
  __syncthreads();
  u16* op = vt + ((size_t)(b * H_KV + kvh) * HD) * T_DIM + tt0;
  #pragma unroll
  for (int i = 0; i < 4; ++i) {
    int cid = tid + i * 256;            // 1024 = 128 d x 8 t-chunks
    int d = cid >> 3, tc = cid & 7;
    u16 vals[8];
    #pragma unroll
    for (int j = 0; j < 8; ++j) vals[j] = tile[tc * 8 + j][d];
    u32x4 w;
    w.x = (unsigned int)vals[0] | ((unsigned int)vals[1] << 16);
    w.y = (unsigned int)vals[2] | ((unsigned int)vals[3] << 16);
    w.z = (unsigned int)vals[4] | ((unsigned int)vals[5] << 16);
    w.w = (unsigned int)vals[6] | ((unsigned int)vals[7] << 16);
    *(u32x4*)(op + (size_t)d * T_DIM + tc * 8) = w;
  }
}

// ---------------- bf16 GEMM: C[M][N] = A[M][K] * Bt[N][K]^T ----------------
// 128x128 tile, BK=64, 4 waves. global_load_lds staging, source pre-swizzled so
// linear LDS writes yield XOR-swizzled content (conflict-free ds_read_b128).
template<int BF16OUT>
__global__ __launch_bounds__(256) void gemm_bt_kernel(const u16* __restrict__ A,
                                                      const u16* __restrict__ Bt,
                                                      void* __restrict__ Cv,
                                                      int M, int N, int K) {
  __shared__ __align__(16) u16 Asm[128 * 64];
  __shared__ __align__(16) u16 Bsm[128 * 64];
  const int tid = threadIdx.x;
  const int lane = tid & 63;
  const int wid = tid >> 6;
  const int m0 = blockIdx.y * 128, n0 = blockIdx.x * 128;
  const int wm = (wid >> 1) * 64, wn = (wid & 1) * 64;
  const int l15 = lane & 15, l4 = lane >> 4;
  const int csrc = (lane & 7) ^ (lane >> 3);      // pre-swizzled source chunk
  f32x4 acc[4][4] = {};

  for (int k0 = 0; k0 < K; k0 += 64) {
    __syncthreads();
    #pragma unroll
    for (int i = 0; i < 4; ++i) {                 // 4 issues/wave/operand, 1KB each
      int g = wid * 4 + i;
      int row = g * 8 + (lane >> 3);
      gl_lds16(A  + (size_t)(m0 + row) * K + k0 + csrc * 8, (char*)Asm + g * 1024);
      gl_lds16(Bt + (size_t)(n0 + row) * K + k0 + csrc * 8, (char*)Bsm + g * 1024);
    }
    __syncthreads();
    #pragma unroll
    for (int ks = 0; ks < 2; ++ks) {
      bf16x8 af[4], bfr[4];
      #pragma unroll
      for (int mf = 0; mf < 4; ++mf) {
        int r = wm + mf * 16 + l15;
        int bo = r * 128 + (((ks * 4 + l4) ^ (r & 7)) * 16);
        af[mf] = __builtin_bit_cast(bf16x8, *(const u32x4*)((const char*)Asm + bo));
      }
      #pragma unroll
      for (int nf = 0; nf < 4; ++nf) {
        int r = wn + nf * 16 + l15;
        int bo = r * 128 + (((ks * 4 + l4) ^ (r & 7)) * 16);
        bfr[nf] = __builtin_bit_cast(bf16x8, *(const u32x4*)((const char*)Bsm + bo));
      }
      #pragma unroll
      for (int mf = 0; mf < 4; ++mf)
        #pragma unroll
        for (int nf = 0; nf < 4; ++nf)
          acc[mf][nf] = mfma16(af[mf], bfr[nf], acc[mf][nf]);
    }
  }
  #pragma unroll
  for (int mf = 0; mf < 4; ++mf)
    #pragma unroll
    for (int nf = 0; nf < 4; ++nf)
      #pragma unroll
      for (int reg = 0; reg < 4; ++reg) {
        int row = m0 + wm + mf * 16 + l4 * 4 + reg;
        int col = n0 + wn + nf * 16 + l15;
        float v = acc[mf][nf][reg];
        if (BF16OUT) ((u16*)Cv)[(size_t)row * N + col] = f2bf(v);
        else         ((float*)Cv)[(size_t)row * N + col] = v;
      }
}

// ---------------- sliding-window GQA flash attention ----------------
// Block = 64 q-rows of one (b,h); 4 waves x 16 rows. K-tiles of 64.
// K / V^T staged via global_load_lds (pre-swizzled source). Longest blocks
// (high qt) dispatch first: LPT packing of the straggler tail.
__global__ __launch_bounds__(256) void attn_kernel(const u16* __restrict__ qkv,
                                                   const u16* __restrict__ vt,
                                                   u16* __restrict__ yb,
                                                   const int* __restrict__ wsz_p) {
  __shared__ __align__(16) u16 Ksm[64 * 128];     // [key][d], 16-chunk swizzle ^(key&15)
  __shared__ __align__(16) u16 Vsm[128 * 64];     // [d][key], 8-chunk swizzle ^(d&7)
  __shared__ __align__(16) u16 Psm[4 * 16 * 64];  // per-wave P 16x64, swizzle ^(q&7)

  const int W = wsz_p[0];
  const int tid = threadIdx.x, lane = tid & 63, wid = tid >> 6;
  const int l15 = lane & 15, l4 = lane >> 4;
  const int bid = blockIdx.x;
  const int h   = bid & 15;
  const int b   = (bid >> 4) & 1;
  const int qt  = 31 - (bid >> 5);       // longest first
  const int kvh = h >> 2;                // rep = 4
  const size_t tokb = (size_t)b * T_DIM;
  const u16* vtb = vt + ((size_t)(b * H_KV + kvh) * HD) * T_DIM;
  const int rbase = qt * 64 + wid * 16;

  // Q fragments (A-layout: row = lane&15, k = (lane>>4)*8 + j)
  bf16x8 qf[4];
  {
    int r = rbase + l15;
    const u16* qp = qkv + (tokb + r) * NQKV + h * HD;
    #pragma unroll
    for (int ks = 0; ks < 4; ++ks)
      qf[ks] = __builtin_bit_cast(bf16x8, *(const u32x4*)(qp + ks * 32 + l4 * 8));
  }

  f32x4 yacc[8] = {};
  float mrow[4], lrow[4];
  #pragma unroll
  for (int rg = 0; rg < 4; ++rg) { mrow[rg] = -3.0e38f; lrow[rg] = 0.0f; }

  const float sc = 0.08838834764831845f * 1.4426950408889634f; // 1/sqrt(128)*log2(e)
  int smin = qt * 64 - W; if (smin < 0) smin = 0;
  const int t0 = smin >> 6;
  char* pbase = (char*)Psm + wid * 2048;

  for (int kt = t0; kt <= qt; ++kt) {
    __syncthreads();
    { // stage K: 16 issues (4/wave), 1KB = 4 key-rows each
      const u16* kp = qkv + (tokb + kt * 64) * NQKV + C_DIM + kvh * HD;
      #pragma unroll
      for (int i = 0; i < 4; ++i) {
        int g = wid * 4 + i;
        int row = g * 4 + (lane >> 4);
        int cs = (lane & 15) ^ (row & 15);
        gl_lds16(kp + (size_t)row * NQKV + cs * 8, (char*)Ksm + g * 1024);
      }
    }
    { // stage V^T: 16 issues (4/wave), 1KB = 8 d-rows each
      const u16* vp = vtb + kt * 64;
      #pragma unroll
      for (int i = 0; i < 4; ++i) {
        int g = wid * 4 + i;
        int d = g * 8 + (lane >> 3);
        int cs = (lane & 7) ^ (d & 7);
        gl_lds16(vp + (size_t)d * T_DIM + cs * 8, (char*)Vsm + g * 1024);
      }
    }
    __syncthreads();

    const int slo = kt * 64;
    bool active = (slo <= rbase + 15) && ((rbase - (slo + 63)) <= W);
    if (active) {
      // S = Q K^T  (16 q-rows x 64 keys per wave)
      float Sc[4][4];
      #pragma unroll
      for (int nf = 0; nf < 4; ++nf) {
        f32x4 sa = {0.f, 0.f, 0.f, 0.f};
        int key = nf * 16 + l15;
        #pragma unroll
        for (int ks = 0; ks < 4; ++ks) {
          int bo = key * 256 + (((ks * 4 + l4) ^ (key & 15)) * 16);
          bf16x8 kf = __builtin_bit_cast(bf16x8, *(const u32x4*)((const char*)Ksm + bo));
          sa = mfma16(qf[ks], kf, sa);
        }
        #pragma unroll
        for (int rg = 0; rg < 4; ++rg) Sc[nf][rg] = sa[rg] * sc;
      }
      // mask only when tile not fully valid for this wave
      bool fullvalid = ((slo + 63) <= rbase) && ((rbase + 15 - slo) <= W);
      if (!fullvalid) {
        #pragma unroll
        for (int nf = 0; nf < 4; ++nf) {
          int s = slo + nf * 16 + l15;
          #pragma unroll
          for (int rg = 0; rg < 4; ++rg) {
            int r = rbase + l4 * 4 + rg;
            if (s > r || (r - s) > W) Sc[nf][rg] = -3.0e38f;
          }
        }
      }
      // online softmax (exp2 domain); clamp guards all-masked rows
      float fmul[4];
      #pragma unroll
      for (int rg = 0; rg < 4; ++rg) {
        float tm = fmaxf(fmaxf(Sc[0][rg], Sc[1][rg]), fmaxf(Sc[2][rg], Sc[3][rg]));
        #pragma unroll
        for (int off = 1; off < 16; off <<= 1) tm = fmaxf(tm, __shfl_xor(tm, off));
        float mnew = fmaxf(mrow[rg], tm);
        float mo = fmaxf(mrow[rg], -1.0e30f);
        float mc = fmaxf(mnew,     -1.0e30f);
        fmul[rg] = exp2f(mo - mc);
        mrow[rg] = mnew;
      }
      float rs[4] = {0.f, 0.f, 0.f, 0.f};
      #pragma unroll
      for (int nf = 0; nf < 4; ++nf)
        #pragma unroll
        for (int rg = 0; rg < 4; ++rg) {
          float mc = fmaxf(mrow[rg], -1.0e30f);
          float pv = exp2f(Sc[nf][rg] - mc);
          rs[rg] += pv;
          // P -> wave-private LDS (bf16, swizzled for A-frag reads)
          int q   = l4 * 4 + rg;
          int key = nf * 16 + l15;
          int bo = q * 128 + (((key >> 3) ^ (q & 7)) * 16) + (key & 7) * 2;
          *(u16*)(pbase + bo) = f2bf(pv);
        }
      #pragma unroll
      for (int rg = 0; rg < 4; ++rg) {
        #pragma unroll
        for (int off = 1; off < 16; off <<= 1) rs[rg] += __shfl_xor(rs[rg], off);
        lrow[rg] = lrow[rg] * fmul[rg] + rs[rg];
      }
      f32x4 fv = {fmul[0], fmul[1], fmul[2], fmul[3]};
      #pragma unroll
      for (int nf2 = 0; nf2 < 8; ++nf2) yacc[nf2] *= fv;

      // PV: y(16 x 128) += P(16 x 64) @ V(64 x 128)
      #pragma unroll
      for (int ks2 = 0; ks2 < 2; ++ks2) {
        int qr = l15;
        int boA = qr * 128 + (((ks2 * 4 + l4) ^ (qr & 7)) * 16);
        bf16x8 pa = __builtin_bit_cast(bf16x8, *(const u32x4*)(pbase + boA));
        #pragma unroll
        for (int nf2 = 0; nf2 < 8; ++nf2) {
          int d = nf2 * 16 + l15;
          int boB = d * 128 + (((ks2 * 4 + l4) ^ (d & 7)) * 16);
          bf16x8 vf = __builtin_bit_cast(bf16x8, *(const u32x4*)((const char*)Vsm + boB));
          yacc[nf2] = mfma16(pa, vf, yacc[nf2]);
        }
      }
    }
  }

  // normalize + write y (bf16)
  #pragma unroll
  for (int nf2 = 0; nf2 < 8; ++nf2)
    #pragma unroll
    for (int rg = 0; rg < 4; ++rg) {
      int r = rbase + l4 * 4 + rg;
      float v = yacc[nf2][rg] / lrow[rg];
      yb[(tokb + r) * (size_t)C_DIM + h * HD + nf2 * 16 + l15] = f2bf(v);
    }
}

// ---------------- launch ----------------
extern "C" void kernel_launch(void* const* d_in, const int* in_sizes, int n_in,
                              void* d_out, int out_size, void* d_ws, size_t ws_size,
                              hipStream_t stream) {
  const float* x    = (const float*)d_in[0];
  const float* cosb = (const float*)d_in[1];
  const float* sinb = (const float*)d_in[2];
  const float* wq   = (const float*)d_in[3];
  const float* wk   = (const float*)d_in[4];
  const float* wv   = (const float*)d_in[5];
  const float* wo   = (const float*)d_in[6];
  const int*   wsz  = (const int*)d_in[7];

  char* ws = (char*)d_ws;
  u16* xb    = (u16*)(ws);                       // 16 MB (dead after QKV GEMM)
  u16* qkvb  = (u16*)(ws + (size_t)16777216);    // 24 MB
  u16* wqkvb = (u16*)(ws + (size_t)41943040);    // 12 MB, [3072][2048]
  u16* wob   = (u16*)(ws + (size_t)54525952);    // 8 MB,  [2048][2048]
  u16* ybuf  = (u16*)(ws + (size_t)62914560);    // 16 MB
  u16* vtb   = (u16*)(ws);                       // 4 MB, reuses xb region

  cast_x_kernel<<<8192, 256, 0, stream>>>(x, xb, MTOK * C_DIM);
  transpose_all_kernel<<<dim3(80, 32), 256, 0, stream>>>(wq, wk, wv, wo, wqkvb, wob);

  gemm_bt_kernel<1><<<dim3(NQKV / 128, MTOK / 128), 256, 0, stream>>>(xb, wqkvb, qkvb, MTOK, NQKV, C_DIM);
  rope_rms_kernel<<<(MTOK * (H_Q + H_KV)) / 4, 256, 0, stream>>>(qkvb, cosb, sinb);
  vtrans_kernel<<<B_DIM * H_KV * (T_DIM / 64), 256, 0, stream>>>(qkvb, vtb);
  attn_kernel<<<B_DIM * H_Q * (T_DIM / 64), 256, 0, stream>>>(qkvb, vtb, ybuf, wsz);
  gemm_bt_kernel<0><<<dim3(C_DIM / 128, MTOK / 128), 256, 0, stream>>>(ybuf, wob, d_out, MTOK, C_DIM, C_DIM);
}